// Round 11
// baseline (555.343 us; speedup 1.0000x reference)
//
#include <hip/hip_runtime.h>
#include <cstdint>

#define BB 32
#define HH 4096
#define FF 4096
#define EE 8
#define NSLOT 16   // 8 experts x 2 slots of <=16 tokens
#define TSEG 16

typedef __attribute__((ext_vector_type(4))) float sf4;
#define AS4 const __attribute__((address_space(4)))

// ---------------------------------------------------------------- gate ----
__global__ __launch_bounds__(256) void gate_kernel(const float* __restrict__ x,
                                                   const float* __restrict__ Wg,
                                                   float* __restrict__ logits) {
  int b = blockIdx.x;
  int tid = threadIdx.x;
  float acc[EE];
#pragma unroll
  for (int e = 0; e < EE; ++e) acc[e] = 0.f;
  const float* xb = x + (size_t)b * HH;
  for (int h = tid; h < HH; h += 256) {
    float xv = xb[h];
    const float4* wg = (const float4*)(Wg + (size_t)h * EE);
    float4 w0 = wg[0], w1 = wg[1];
    acc[0] = fmaf(xv, w0.x, acc[0]);
    acc[1] = fmaf(xv, w0.y, acc[1]);
    acc[2] = fmaf(xv, w0.z, acc[2]);
    acc[3] = fmaf(xv, w0.w, acc[3]);
    acc[4] = fmaf(xv, w1.x, acc[4]);
    acc[5] = fmaf(xv, w1.y, acc[5]);
    acc[6] = fmaf(xv, w1.z, acc[6]);
    acc[7] = fmaf(xv, w1.w, acc[7]);
  }
#pragma unroll
  for (int off = 32; off > 0; off >>= 1) {
#pragma unroll
    for (int e = 0; e < EE; ++e) acc[e] += __shfl_down(acc[e], off, 64);
  }
  __shared__ float part[4][EE];
  if ((tid & 63) == 0) {
#pragma unroll
    for (int e = 0; e < EE; ++e) part[tid >> 6][e] = acc[e];
  }
  __syncthreads();
  if (tid < EE) {
    logits[(size_t)b * EE + tid] =
        part[0][tid] + part[1][tid] + part[2][tid] + part[3][tid];
  }
}

// --------------------------------------------------------------- route ----
__global__ void route_kernel(const float* __restrict__ logits,
                             int* __restrict__ cnt,
                             int* __restrict__ tok,
                             float* __restrict__ wts,
                             int* __restrict__ ord) {
  if (threadIdx.x != 0 || blockIdx.x != 0) return;
  int e0[BB], e1[BB];
  float p0[BB], p1[BB];
  for (int b = 0; b < BB; ++b) {
    const float* L = logits + (size_t)b * EE;
    int i0 = 0;
    float v0 = L[0];
    for (int e = 1; e < EE; ++e) {
      float v = L[e];
      if (v > v0) { v0 = v; i0 = e; }
    }
    int i1 = (i0 == 0) ? 1 : 0;
    float v1 = L[i1];
    for (int e = 0; e < EE; ++e) {
      if (e == i0) continue;
      float v = L[e];
      if (v > v1) { v1 = v; i1 = e; }
    }
    float p = 1.f / (1.f + __expf(v1 - v0));
    e0[b] = i0; e1[b] = i1; p0[b] = p; p1[b] = 1.f - p;
  }
  for (int s = 0; s < NSLOT; ++s) {
    cnt[s] = 0;
    for (int t = 0; t < TSEG; ++t) { tok[s * TSEG + t] = 0; wts[s * TSEG + t] = 0.f; }
  }
  for (int e = 0; e < EE; ++e) {
    int c = 0;
    for (int b = 0; b < BB; ++b) {
      float w = 0.f;
      int sel = 0;
      if (e0[b] == e) { w = p0[b]; sel = 1; }
      else if (e1[b] == e) { w = p1[b]; sel = 1; }
      if (sel) {
        int s = e * 2 + (c >> 4);
        int t = c & 15;
        tok[s * TSEG + t] = b;
        wts[s * TSEG + t] = w;
        cnt[s] = t + 1;
        ++c;
      }
    }
  }
  int na = 0;
  for (int s = 0; s < NSLOT; ++s) if (cnt[s] > 0) ord[na++] = s;
  for (int s = 0; s < NSLOT; ++s) if (cnt[s] == 0) ord[na++] = s;
}

// -------------------------------------------------------------- buildx ----
__global__ __launch_bounds__(256) void buildx_kernel(const float* __restrict__ x,
                                                     const int* __restrict__ cnt,
                                                     const int* __restrict__ tok,
                                                     float* __restrict__ xseg) {
  int s = blockIdx.y;
  int c = cnt[s];
  if (c == 0) return;
  int tid = threadIdx.x;
  int t = tid & 15;
  int hoff = tid >> 4;
  int tk = tok[s * TSEG + t];
  bool act = t < c;
  int hbase = blockIdx.x * 256;
#pragma unroll
  for (int i = 0; i < 16; ++i) {
    int h = hbase + i * 16 + hoff;
    float v = act ? x[(size_t)tk * HH + h] : 0.f;
    xseg[((size_t)s * HH + h) * TSEG + t] = v;
  }
}

// ----------------------------------------------------------- core math ----
// Barrier-free wave-independent stream. Weight: dword/lane (256 B/wave,
// coalesced), depth-16 consume-oldest register ring = the ONLY vmcnt
// traffic. x: wave-uniform scalar reads through the konstant cache
// (address_space(4) -> s_load_dwordx4, lgkmcnt) feeding v_fma SGPR operands.
__device__ __forceinline__ void fma16x(float* __restrict__ acc, float wv,
                                       sf4 x0, sf4 x1, sf4 x2, sf4 x3) {
  acc[0]  = fmaf(x0.x, wv, acc[0]);
  acc[1]  = fmaf(x0.y, wv, acc[1]);
  acc[2]  = fmaf(x0.z, wv, acc[2]);
  acc[3]  = fmaf(x0.w, wv, acc[3]);
  acc[4]  = fmaf(x1.x, wv, acc[4]);
  acc[5]  = fmaf(x1.y, wv, acc[5]);
  acc[6]  = fmaf(x1.z, wv, acc[6]);
  acc[7]  = fmaf(x1.w, wv, acc[7]);
  acc[8]  = fmaf(x2.x, wv, acc[8]);
  acc[9]  = fmaf(x2.y, wv, acc[9]);
  acc[10] = fmaf(x2.z, wv, acc[10]);
  acc[11] = fmaf(x2.w, wv, acc[11]);
  acc[12] = fmaf(x3.x, wv, acc[12]);
  acc[13] = fmaf(x3.y, wv, acc[13]);
  acc[14] = fmaf(x3.z, wv, acc[14]);
  acc[15] = fmaf(x3.w, wv, acc[15]);
}

__device__ __forceinline__ void accum_sc(float* __restrict__ acc,
                                         const float* __restrict__ wp,
                                         AS4 sf4* __restrict__ xc, int rows) {
  float ring[16];
#pragma unroll
  for (int k = 0; k < 16; ++k) ring[k] = wp[(size_t)k * 4096];
  int i0 = 0;
  for (; i0 + 16 < rows; i0 += 16) {
#pragma unroll
    for (int k = 0; k < 16; ++k) {
      float wv = ring[k];
      ring[k] = wp[(size_t)(i0 + 16 + k) * 4096];
      AS4 sf4* xr = xc + (size_t)(i0 + k) * 4;
      fma16x(acc, wv, xr[0], xr[1], xr[2], xr[3]);
    }
  }
#pragma unroll
  for (int k = 0; k < 16; ++k) {
    AS4 sf4* xr = xc + (size_t)(rows - 16 + k) * 4;
    fma16x(acc, ring[k], xr[0], xr[1], xr[2], xr[3]);
  }
}

// --------------------------------------------------------------- passB ----
// Wave(=block, 64 thr) = (64-col strip, slot, mat, K-half z). Lane = 1 col x
// 16 toks. Partials stored to plane z (no atomics, no barriers, no LDS).
__global__ __launch_bounds__(64) void passB11_kernel(const float* __restrict__ W1,
                                                     const float* __restrict__ W3,
                                                     const float* __restrict__ xseg,
                                                     float* __restrict__ h1p,
                                                     float* __restrict__ h3p,
                                                     const int* __restrict__ cnt,
                                                     const int* __restrict__ ord) {
  int y = blockIdx.y;
  int sIdx = y >> 2;
  int mat = (y >> 1) & 1;
  int z = y & 1;
  int s = ord[sIdx];
  if (cnt[s] == 0) return;
  int e = s >> 1;
  int col = blockIdx.x * 64 + threadIdx.x;
  const float* wp = (mat ? W3 : W1) + (size_t)e * HH * FF +
                    (size_t)z * 2048 * FF + col;
  AS4 sf4* xc = (AS4 sf4*)(xseg + ((size_t)s * HH + (size_t)z * 2048) * TSEG);
  float acc[16];
#pragma unroll
  for (int t = 0; t < 16; ++t) acc[t] = 0.f;
  accum_sc(acc, wp, xc, 2048);
  float* hp = (mat ? h3p : h1p) +
              (((size_t)z * NSLOT + s) * FF + col) * TSEG;
  *(float4*)(hp + 0)  = make_float4(acc[0], acc[1], acc[2], acc[3]);
  *(float4*)(hp + 4)  = make_float4(acc[4], acc[5], acc[6], acc[7]);
  *(float4*)(hp + 8)  = make_float4(acc[8], acc[9], acc[10], acc[11]);
  *(float4*)(hp + 12) = make_float4(acc[12], acc[13], acc[14], acc[15]);
}

// ------------------------------------------------------------- combine ----
// g = silu(h1p0+h1p1) * (h3p0+h3p1), active slots only.
__global__ __launch_bounds__(256) void combine11_kernel(const float* __restrict__ h1p,
                                                        const float* __restrict__ h3p,
                                                        float* __restrict__ g,
                                                        const int* __restrict__ cnt) {
  int s = blockIdx.y;
  if (cnt[s] == 0) return;
  size_t base = (size_t)s * (FF * TSEG / 4);
  size_t plane = (size_t)NSLOT * (FF * TSEG / 4);
  size_t i = base + (size_t)blockIdx.x * 256 + threadIdx.x;
  float4 a0 = ((const float4*)h1p)[i];
  float4 a1 = ((const float4*)h1p)[plane + i];
  float4 b0 = ((const float4*)h3p)[i];
  float4 b1 = ((const float4*)h3p)[plane + i];
  float4 h1 = make_float4(a0.x + a1.x, a0.y + a1.y, a0.z + a1.z, a0.w + a1.w);
  float4 h3 = make_float4(b0.x + b1.x, b0.y + b1.y, b0.z + b1.z, b0.w + b1.w);
  float4 r;
  r.x = (h1.x / (1.f + __expf(-h1.x))) * h3.x;
  r.y = (h1.y / (1.f + __expf(-h1.y))) * h3.y;
  r.z = (h1.z / (1.f + __expf(-h1.z))) * h3.z;
  r.w = (h1.w / (1.f + __expf(-h1.w))) * h3.w;
  ((float4*)g)[i] = r;
}

// --------------------------------------------------------------- passC ----
// Wave = (64-col strip of H, slot, K-quarter z). Lane = 1 col x 16 toks.
// Epilogue: <=c weighted atomics/lane into out (<=8 adds per element).
__global__ __launch_bounds__(64) void passC11_kernel(const float* __restrict__ W2,
                                                     const float* __restrict__ g,
                                                     const int* __restrict__ cnt,
                                                     const int* __restrict__ tok,
                                                     const float* __restrict__ wts,
                                                     const int* __restrict__ ord,
                                                     float* __restrict__ out) {
  int y = blockIdx.y;
  int sIdx = y >> 2;
  int z = y & 3;
  int s = ord[sIdx];
  int c = cnt[s];
  if (c == 0) return;
  int e = s >> 1;
  int col = blockIdx.x * 64 + threadIdx.x;
  const float* wp = W2 + (size_t)e * FF * HH + (size_t)z * 1024 * HH + col;
  AS4 sf4* gc = (AS4 sf4*)(g + ((size_t)s * FF + (size_t)z * 1024) * TSEG);
  float acc[16];
#pragma unroll
  for (int t = 0; t < 16; ++t) acc[t] = 0.f;
  accum_sc(acc, wp, gc, 1024);
#pragma unroll
  for (int t = 0; t < 16; ++t) {
    if (t < c) {
      atomicAdd(out + (size_t)tok[s * TSEG + t] * HH + col,
                wts[s * TSEG + t] * acc[t]);
    }
  }
}

// -------------------------------------------------------------- launch ----
extern "C" void kernel_launch(void* const* d_in, const int* in_sizes, int n_in,
                              void* d_out, int out_size, void* d_ws, size_t ws_size,
                              hipStream_t stream) {
  const float* x  = (const float*)d_in[0];
  const float* Wg = (const float*)d_in[1];
  const float* W1 = (const float*)d_in[2];
  const float* W3 = (const float*)d_in[3];
  const float* W2 = (const float*)d_in[4];
  float* out = (float*)d_out;

  char* ws = (char*)d_ws;
  float* logits = (float*)ws;                 // 256 f32
  int*   cnt    = (int*)(ws + 1024);          // 16 i32
  int*   tok    = (int*)(ws + 1088);          // 256 i32
  float* wts    = (float*)(ws + 2112);        // 256 f32
  int*   ord    = (int*)(ws + 3136);          // 16 i32
  float* xseg   = (float*)(ws + 4096);                  // 4 MB
  float* h1p    = xseg + (size_t)NSLOT * HH * TSEG;     // 8 MB (2 planes)
  float* h3p    = h1p + (size_t)2 * NSLOT * FF * TSEG;  // 8 MB (2 planes)
  float* g      = h3p + (size_t)2 * NSLOT * FF * TSEG;  // 4 MB

  hipMemsetAsync(d_out, 0, (size_t)out_size * sizeof(float), stream);
  gate_kernel<<<BB, 256, 0, stream>>>(x, Wg, logits);
  route_kernel<<<1, 64, 0, stream>>>(logits, cnt, tok, wts, ord);
  buildx_kernel<<<dim3(HH / 256, NSLOT), 256, 0, stream>>>(x, cnt, tok, xseg);
  passB11_kernel<<<dim3(FF / 64, NSLOT * 4), 64, 0, stream>>>(W1, W3, xseg, h1p, h3p, cnt, ord);
  combine11_kernel<<<dim3(FF * TSEG / 1024, NSLOT), 256, 0, stream>>>(h1p, h3p, g, cnt);
  passC11_kernel<<<dim3(HH / 64, NSLOT * 4), 64, 0, stream>>>(W2, g, cnt, tok, wts, ord, out);
}

// Round 12
// 393.468 us; speedup vs baseline: 1.4114x; 1.4114x over previous
//
#include <hip/hip_runtime.h>
#include <cstdint>

#define BB 32
#define HH 4096
#define FF 4096
#define EE 8
#define NSLOT 16   // 8 experts x 2 slots of <=16 tokens
#define TSEG 16
#define CH 512     // rows staged per chunk
#define RSTR 36    // reduce stride (floats, 16B-aligned)

// ---------------------------------------------------------------- gate ----
__global__ __launch_bounds__(256) void gate_kernel(const float* __restrict__ x,
                                                   const float* __restrict__ Wg,
                                                   float* __restrict__ logits) {
  int b = blockIdx.x;
  int tid = threadIdx.x;
  float acc[EE];
#pragma unroll
  for (int e = 0; e < EE; ++e) acc[e] = 0.f;
  const float* xb = x + (size_t)b * HH;
  for (int h = tid; h < HH; h += 256) {
    float xv = xb[h];
    const float4* wg = (const float4*)(Wg + (size_t)h * EE);
    float4 w0 = wg[0], w1 = wg[1];
    acc[0] = fmaf(xv, w0.x, acc[0]);
    acc[1] = fmaf(xv, w0.y, acc[1]);
    acc[2] = fmaf(xv, w0.z, acc[2]);
    acc[3] = fmaf(xv, w0.w, acc[3]);
    acc[4] = fmaf(xv, w1.x, acc[4]);
    acc[5] = fmaf(xv, w1.y, acc[5]);
    acc[6] = fmaf(xv, w1.z, acc[6]);
    acc[7] = fmaf(xv, w1.w, acc[7]);
  }
#pragma unroll
  for (int off = 32; off > 0; off >>= 1) {
#pragma unroll
    for (int e = 0; e < EE; ++e) acc[e] += __shfl_down(acc[e], off, 64);
  }
  __shared__ float part[4][EE];
  if ((tid & 63) == 0) {
#pragma unroll
    for (int e = 0; e < EE; ++e) part[tid >> 6][e] = acc[e];
  }
  __syncthreads();
  if (tid < EE) {
    logits[(size_t)b * EE + tid] =
        part[0][tid] + part[1][tid] + part[2][tid] + part[3][tid];
  }
}

// --------------------------------------------------------------- route ----
__global__ void route_kernel(const float* __restrict__ logits,
                             int* __restrict__ cnt,
                             int* __restrict__ tok,
                             float* __restrict__ wts,
                             int* __restrict__ ord) {
  if (threadIdx.x != 0 || blockIdx.x != 0) return;
  int e0[BB], e1[BB];
  float p0[BB], p1[BB];
  for (int b = 0; b < BB; ++b) {
    const float* L = logits + (size_t)b * EE;
    int i0 = 0;
    float v0 = L[0];
    for (int e = 1; e < EE; ++e) {
      float v = L[e];
      if (v > v0) { v0 = v; i0 = e; }
    }
    int i1 = (i0 == 0) ? 1 : 0;
    float v1 = L[i1];
    for (int e = 0; e < EE; ++e) {
      if (e == i0) continue;
      float v = L[e];
      if (v > v1) { v1 = v; i1 = e; }
    }
    float p = 1.f / (1.f + __expf(v1 - v0));
    e0[b] = i0; e1[b] = i1; p0[b] = p; p1[b] = 1.f - p;
  }
  for (int s = 0; s < NSLOT; ++s) {
    cnt[s] = 0;
    for (int t = 0; t < TSEG; ++t) { tok[s * TSEG + t] = 0; wts[s * TSEG + t] = 0.f; }
  }
  for (int e = 0; e < EE; ++e) {
    int c = 0;
    for (int b = 0; b < BB; ++b) {
      float w = 0.f;
      int sel = 0;
      if (e0[b] == e) { w = p0[b]; sel = 1; }
      else if (e1[b] == e) { w = p1[b]; sel = 1; }
      if (sel) {
        int s = e * 2 + (c >> 4);
        int t = c & 15;
        tok[s * TSEG + t] = b;
        wts[s * TSEG + t] = w;
        cnt[s] = t + 1;
        ++c;
      }
    }
  }
  int na = 0;
  for (int s = 0; s < NSLOT; ++s) if (cnt[s] > 0) ord[na++] = s;
  for (int s = 0; s < NSLOT; ++s) if (cnt[s] == 0) ord[na++] = s;
}

// -------------------------------------------------------------- buildx ----
__global__ __launch_bounds__(256) void buildx_kernel(const float* __restrict__ x,
                                                     const int* __restrict__ cnt,
                                                     const int* __restrict__ tok,
                                                     float* __restrict__ xseg) {
  int s = blockIdx.y;
  int c = cnt[s];
  if (c == 0) return;
  int tid = threadIdx.x;
  int t = tid & 15;
  int hoff = tid >> 4;
  int tk = tok[s * TSEG + t];
  bool act = t < c;
  int hbase = blockIdx.x * 256;
#pragma unroll
  for (int i = 0; i < 16; ++i) {
    int h = hbase + i * 16 + hoff;
    float v = act ? x[(size_t)tk * HH + h] : 0.f;
    xseg[((size_t)s * HH + h) * TSEG + t] = v;
  }
}

// ----------------------------------------------------------- core math ----
// Lane covers 4 cols (float4 weight) x 8 tokens (half-wave split).
// 128 rows per call, depth-8 float4 weight ring (vmcnt only); xs = 2 b128
// broadcast reads per row from LDS (lgkmcnt).
__device__ __forceinline__ void fma8(float4* __restrict__ acc,
                                     const float* __restrict__ xr, float4 wv) {
  float xs[8];
  *(float4*)&xs[0] = *(const float4*)(xr);
  *(float4*)&xs[4] = *(const float4*)(xr + 4);
#pragma unroll
  for (int t = 0; t < 8; ++t) {
    acc[t].x = fmaf(xs[t], wv.x, acc[t].x);
    acc[t].y = fmaf(xs[t], wv.y, acc[t].y);
    acc[t].z = fmaf(xs[t], wv.z, acc[t].z);
    acc[t].w = fmaf(xs[t], wv.w, acc[t].w);
  }
}

__device__ __forceinline__ void accum128(float4* __restrict__ acc,
                                         const float4* __restrict__ wp4,
                                         const float* __restrict__ lxw,
                                         int half8) {
  float4 ring[8];
#pragma unroll
  for (int k = 0; k < 8; ++k) ring[k] = wp4[(size_t)k * 1024];
  for (int i0 = 0; i0 + 8 < 128; i0 += 8) {
#pragma unroll
    for (int k = 0; k < 8; ++k) {
      float4 wv = ring[k];
      ring[k] = wp4[(size_t)(i0 + 8 + k) * 1024];
      fma8(acc, lxw + (i0 + k) * TSEG + half8, wv);
    }
  }
#pragma unroll
  for (int k = 0; k < 8; ++k)
    fma8(acc, lxw + (120 + k) * TSEG + half8, ring[k]);
}

// Stage CH=512 rows x 16 floats (linear 32 KB copy).
__device__ __forceinline__ void stage512(float* __restrict__ lx,
                                         const float* __restrict__ src, int tid) {
  const float4* s4 = (const float4*)src;
  float4* d4 = (float4*)lx;
#pragma unroll
  for (int k = 0; k < 8; ++k) d4[k * 256 + tid] = s4[k * 256 + tid];
}

// Stage with fused z-sum + silu: g = silu(h1a+h1b) * (h3a+h3b).
__device__ __forceinline__ void stage_sum_silu512(float* __restrict__ lx,
                                                  const float* __restrict__ h1a,
                                                  const float* __restrict__ h1b,
                                                  const float* __restrict__ h3a,
                                                  const float* __restrict__ h3b,
                                                  int tid) {
  const float4* a4 = (const float4*)h1a;
  const float4* a4b = (const float4*)h1b;
  const float4* b4 = (const float4*)h3a;
  const float4* b4b = (const float4*)h3b;
  float4* d4 = (float4*)lx;
#pragma unroll
  for (int k = 0; k < 8; ++k) {
    int q = k * 256 + tid;
    float4 p = a4[q], pb = a4b[q];
    float4 r = b4[q], rb = b4b[q];
    float4 h1 = make_float4(p.x + pb.x, p.y + pb.y, p.z + pb.z, p.w + pb.w);
    float4 h3 = make_float4(r.x + rb.x, r.y + rb.y, r.z + rb.z, r.w + rb.w);
    float4 g;
    g.x = (h1.x / (1.f + __expf(-h1.x))) * h3.x;
    g.y = (h1.y / (1.f + __expf(-h1.y))) * h3.y;
    g.z = (h1.z / (1.f + __expf(-h1.z))) * h3.z;
    g.w = (h1.w / (1.f + __expf(-h1.w))) * h3.w;
    d4[q] = g;
  }
}

// Write per-lane acc (4 cols x 8 toks) into the reduce scratch.
__device__ __forceinline__ void red_write(float* __restrict__ lds,
                                          const float4* __restrict__ acc, int tid) {
  int l = tid & 63;
  int w = tid >> 6;
  float tmp[32];
#pragma unroll
  for (int t = 0; t < 8; ++t) {
    tmp[t] = acc[t].x;
    tmp[8 + t] = acc[t].y;
    tmp[16 + t] = acc[t].z;
    tmp[24 + t] = acc[t].w;
  }
  float* rp = lds + (size_t)(w * 64 + l) * RSTR;
#pragma unroll
  for (int q = 0; q < 32; q += 4) *(float4*)(rp + q) = *(const float4*)&tmp[q];
}

// Reader: thread = (col 0..127, half 0..1); sums 4 waves for 8 tokens.
__device__ __forceinline__ void red_read(const float* __restrict__ lds,
                                         float* __restrict__ v, int tid) {
  int col = tid & 127;
  int half = tid >> 7;
  int base = (half * 32 + (col >> 2)) * RSTR + (col & 3) * 8;
#pragma unroll
  for (int t = 0; t < 8; ++t) {
    float sum = 0.f;
#pragma unroll
    for (int w = 0; w < 4; ++w) sum += lds[w * 64 * RSTR + base + t];
    v[t] = sum;
  }
}

// --------------------------------------------------------------- passB ----
// Block: one matrix, 128 f-cols, row-half z of 2048 rows (4 chunks of 512,
// 4 waves x 128 rows each). Partials to plane z; LDS reduce, plain stores.
__global__ __launch_bounds__(256) void passB12_kernel(const float* __restrict__ W1,
                                                      const float* __restrict__ W3,
                                                      const float* __restrict__ xseg,
                                                      float* __restrict__ h1p,
                                                      float* __restrict__ h3p,
                                                      const int* __restrict__ cnt,
                                                      const int* __restrict__ ord) {
  __shared__ float lds[4 * 64 * RSTR];  // 36.9 KB (>= 32 KB stage)
  int gy = blockIdx.y;
  int s = ord[gy >> 2];
  int mat = (gy >> 1) & 1;
  int z = gy & 1;
  int c = cnt[s];
  if (c == 0) return;
  int e = s >> 1;
  int tid = threadIdx.x;
  int l = tid & 63;
  int w = tid >> 6;
  int colbase = blockIdx.x * 128;
  const float* Wm = (mat ? W3 : W1) + (size_t)e * HH * FF +
                    (size_t)z * 2048 * FF + colbase + (l & 31) * 4;
  const float* xsrc = xseg + ((size_t)s * HH + (size_t)z * 2048) * TSEG;
  int half8 = (l >> 5) * 8;
  float4 acc[8];
#pragma unroll
  for (int t = 0; t < 8; ++t) acc[t] = make_float4(0.f, 0.f, 0.f, 0.f);
  for (int ch = 0; ch < 4; ++ch) {
    __syncthreads();
    stage512(lds, xsrc + (size_t)(ch * CH) * TSEG, tid);
    __syncthreads();
    const float4* wp4 = (const float4*)(Wm + (size_t)(ch * CH + w * 128) * FF);
    accum128(acc, wp4, lds + (w * 128) * TSEG, half8);
  }
  __syncthreads();
  red_write(lds, acc, tid);
  __syncthreads();
  float v[8];
  red_read(lds, v, tid);
  int col = tid & 127;
  int half = tid >> 7;
  float* seg = (mat ? h3p : h1p) +
               (((size_t)z * NSLOT + s) * FF + colbase + col) * TSEG + half * 8;
  *(float4*)(seg) = *(const float4*)&v[0];
  *(float4*)(seg + 4) = *(const float4*)&v[4];
}

// --------------------------------------------------------------- passC ----
// Block: 128 h-cols, rows [z*1024,+1024) of W2 (2 chunks); staging fuses
// z-sum + silu; epilogue reduce + weighted atomics (<=8 adds/element).
__global__ __launch_bounds__(256) void passC12_kernel(const float* __restrict__ W2,
                                                      const float* __restrict__ h1p,
                                                      const float* __restrict__ h3p,
                                                      const int* __restrict__ cnt,
                                                      const int* __restrict__ tok,
                                                      const float* __restrict__ wts,
                                                      const int* __restrict__ ord,
                                                      float* __restrict__ out) {
  __shared__ float lds[4 * 64 * RSTR];
  __shared__ int stok[TSEG];
  __shared__ float swt[TSEG];
  int gy = blockIdx.y;
  int s = ord[gy >> 2];
  int z = gy & 3;
  int c = cnt[s];
  if (c == 0) return;
  int e = s >> 1;
  int tid = threadIdx.x;
  int l = tid & 63;
  int w = tid >> 6;
  int colbase = blockIdx.x * 128;
  if (tid < TSEG) {
    stok[tid] = tok[s * TSEG + tid];
    swt[tid] = wts[s * TSEG + tid];
  }
  const float* Wm = W2 + (size_t)e * FF * HH + (size_t)z * 1024 * HH +
                    colbase + (l & 31) * 4;
  size_t rowoff = ((size_t)s * FF + (size_t)z * 1024) * TSEG;
  size_t plane = (size_t)NSLOT * FF * TSEG;
  const float* h1a = h1p + rowoff;
  const float* h1b = h1p + plane + rowoff;
  const float* h3a = h3p + rowoff;
  const float* h3b = h3p + plane + rowoff;
  int half8 = (l >> 5) * 8;
  float4 acc[8];
#pragma unroll
  for (int t = 0; t < 8; ++t) acc[t] = make_float4(0.f, 0.f, 0.f, 0.f);
  for (int ch = 0; ch < 2; ++ch) {
    __syncthreads();
    size_t o = (size_t)(ch * CH) * TSEG;
    stage_sum_silu512(lds, h1a + o, h1b + o, h3a + o, h3b + o, tid);
    __syncthreads();
    const float4* wp4 = (const float4*)(Wm + (size_t)(ch * CH + w * 128) * HH);
    accum128(acc, wp4, lds + (w * 128) * TSEG, half8);
  }
  __syncthreads();
  red_write(lds, acc, tid);
  __syncthreads();
  float v[8];
  red_read(lds, v, tid);
  int col = tid & 127;
  int half = tid >> 7;
  float* op = out + colbase + col;
#pragma unroll
  for (int t = 0; t < 8; ++t) {
    int tt = half * 8 + t;
    if (tt < c) atomicAdd(op + (size_t)stok[tt] * HH, swt[tt] * v[t]);
  }
}

// -------------------------------------------------------------- launch ----
extern "C" void kernel_launch(void* const* d_in, const int* in_sizes, int n_in,
                              void* d_out, int out_size, void* d_ws, size_t ws_size,
                              hipStream_t stream) {
  const float* x  = (const float*)d_in[0];
  const float* Wg = (const float*)d_in[1];
  const float* W1 = (const float*)d_in[2];
  const float* W3 = (const float*)d_in[3];
  const float* W2 = (const float*)d_in[4];
  float* out = (float*)d_out;

  char* ws = (char*)d_ws;
  float* logits = (float*)ws;                 // 256 f32
  int*   cnt    = (int*)(ws + 1024);          // 16 i32
  int*   tok    = (int*)(ws + 1088);          // 256 i32
  float* wts    = (float*)(ws + 2112);        // 256 f32
  int*   ord    = (int*)(ws + 3136);          // 16 i32
  float* xseg   = (float*)(ws + 4096);                  // 4 MB
  float* h1p    = xseg + (size_t)NSLOT * HH * TSEG;     // 8 MB (2 z-planes)
  float* h3p    = h1p + (size_t)2 * NSLOT * FF * TSEG;  // 8 MB (2 z-planes)

  hipMemsetAsync(d_out, 0, (size_t)out_size * sizeof(float), stream);
  gate_kernel<<<BB, 256, 0, stream>>>(x, Wg, logits);
  route_kernel<<<1, 64, 0, stream>>>(logits, cnt, tok, wts, ord);
  buildx_kernel<<<dim3(HH / 256, NSLOT), 256, 0, stream>>>(x, cnt, tok, xseg);
  passB12_kernel<<<dim3(FF / 128, NSLOT * 4), 256, 0, stream>>>(W1, W3, xseg, h1p, h3p, cnt, ord);
  passC12_kernel<<<dim3(HH / 128, NSLOT * 4), 256, 0, stream>>>(W2, h1p, h3p, cnt, tok, wts, ord, out);
}

// Round 13
// 357.948 us; speedup vs baseline: 1.5515x; 1.0992x over previous
//
#include <hip/hip_runtime.h>
#include <cstdint>

#define BB 32
#define HH 4096
#define FF 4096
#define EE 8
#define NSLOT 16   // 8 experts x 2 slots of <=16 tokens
#define TSEG 16
#define CH 512     // rows staged per chunk
#define RSTR 36    // reduce stride NT16 (floats)
#define RSTR8 18   // reduce stride NT8

// ---------------------------------------------------------------- gate ----
__global__ __launch_bounds__(256) void gate_kernel(const float* __restrict__ x,
                                                   const float* __restrict__ Wg,
                                                   float* __restrict__ logits) {
  int b = blockIdx.x;
  int tid = threadIdx.x;
  float acc[EE];
#pragma unroll
  for (int e = 0; e < EE; ++e) acc[e] = 0.f;
  const float* xb = x + (size_t)b * HH;
  for (int h = tid; h < HH; h += 256) {
    float xv = xb[h];
    const float4* wg = (const float4*)(Wg + (size_t)h * EE);
    float4 w0 = wg[0], w1 = wg[1];
    acc[0] = fmaf(xv, w0.x, acc[0]);
    acc[1] = fmaf(xv, w0.y, acc[1]);
    acc[2] = fmaf(xv, w0.z, acc[2]);
    acc[3] = fmaf(xv, w0.w, acc[3]);
    acc[4] = fmaf(xv, w1.x, acc[4]);
    acc[5] = fmaf(xv, w1.y, acc[5]);
    acc[6] = fmaf(xv, w1.z, acc[6]);
    acc[7] = fmaf(xv, w1.w, acc[7]);
  }
#pragma unroll
  for (int off = 32; off > 0; off >>= 1) {
#pragma unroll
    for (int e = 0; e < EE; ++e) acc[e] += __shfl_down(acc[e], off, 64);
  }
  __shared__ float part[4][EE];
  if ((tid & 63) == 0) {
#pragma unroll
    for (int e = 0; e < EE; ++e) part[tid >> 6][e] = acc[e];
  }
  __syncthreads();
  if (tid < EE) {
    logits[(size_t)b * EE + tid] =
        part[0][tid] + part[1][tid] + part[2][tid] + part[3][tid];
  }
}

// --------------------------------------------------------------- route ----
__global__ void route_kernel(const float* __restrict__ logits,
                             int* __restrict__ cnt,
                             int* __restrict__ tok,
                             float* __restrict__ wts,
                             int* __restrict__ ord) {
  if (threadIdx.x != 0 || blockIdx.x != 0) return;
  int e0[BB], e1[BB];
  float p0[BB], p1[BB];
  for (int b = 0; b < BB; ++b) {
    const float* L = logits + (size_t)b * EE;
    int i0 = 0;
    float v0 = L[0];
    for (int e = 1; e < EE; ++e) {
      float v = L[e];
      if (v > v0) { v0 = v; i0 = e; }
    }
    int i1 = (i0 == 0) ? 1 : 0;
    float v1 = L[i1];
    for (int e = 0; e < EE; ++e) {
      if (e == i0) continue;
      float v = L[e];
      if (v > v1) { v1 = v; i1 = e; }
    }
    float p = 1.f / (1.f + __expf(v1 - v0));
    e0[b] = i0; e1[b] = i1; p0[b] = p; p1[b] = 1.f - p;
  }
  for (int s = 0; s < NSLOT; ++s) {
    cnt[s] = 0;
    for (int t = 0; t < TSEG; ++t) { tok[s * TSEG + t] = 0; wts[s * TSEG + t] = 0.f; }
  }
  for (int e = 0; e < EE; ++e) {
    int c = 0;
    for (int b = 0; b < BB; ++b) {
      float w = 0.f;
      int sel = 0;
      if (e0[b] == e) { w = p0[b]; sel = 1; }
      else if (e1[b] == e) { w = p1[b]; sel = 1; }
      if (sel) {
        int s = e * 2 + (c >> 4);
        int t = c & 15;
        tok[s * TSEG + t] = b;
        wts[s * TSEG + t] = w;
        cnt[s] = t + 1;
        ++c;
      }
    }
  }
  int na = 0;
  for (int s = 0; s < NSLOT; ++s) if (cnt[s] > 0) ord[na++] = s;
  for (int s = 0; s < NSLOT; ++s) if (cnt[s] == 0) ord[na++] = s;
}

// -------------------------------------------------------------- buildx ----
__global__ __launch_bounds__(256) void buildx_kernel(const float* __restrict__ x,
                                                     const int* __restrict__ cnt,
                                                     const int* __restrict__ tok,
                                                     float* __restrict__ xseg) {
  int s = blockIdx.y;
  int c = cnt[s];
  if (c == 0) return;
  int tid = threadIdx.x;
  int t = tid & 15;
  int hoff = tid >> 4;
  int tk = tok[s * TSEG + t];
  bool act = t < c;
  int hbase = blockIdx.x * 256;
#pragma unroll
  for (int i = 0; i < 16; ++i) {
    int h = hbase + i * 16 + hoff;
    float v = act ? x[(size_t)tk * HH + h] : 0.f;
    xseg[((size_t)s * HH + h) * TSEG + t] = v;
  }
}

// ------------------------------------------------------ core math NT16 ----
__device__ __forceinline__ void fma8(float4* __restrict__ acc,
                                     const float* __restrict__ xr, float4 wv) {
  float xs[8];
  *(float4*)&xs[0] = *(const float4*)(xr);
  *(float4*)&xs[4] = *(const float4*)(xr + 4);
#pragma unroll
  for (int t = 0; t < 8; ++t) {
    acc[t].x = fmaf(xs[t], wv.x, acc[t].x);
    acc[t].y = fmaf(xs[t], wv.y, acc[t].y);
    acc[t].z = fmaf(xs[t], wv.z, acc[t].z);
    acc[t].w = fmaf(xs[t], wv.w, acc[t].w);
  }
}

__device__ __forceinline__ void accum128(float4* __restrict__ acc,
                                         const float4* __restrict__ wp4,
                                         const float* __restrict__ lxw,
                                         int half8) {
  float4 ring[8];
#pragma unroll
  for (int k = 0; k < 8; ++k) ring[k] = wp4[(size_t)k * 1024];
  for (int i0 = 0; i0 + 8 < 128; i0 += 8) {
#pragma unroll
    for (int k = 0; k < 8; ++k) {
      float4 wv = ring[k];
      ring[k] = wp4[(size_t)(i0 + 8 + k) * 1024];
      fma8(acc, lxw + (i0 + k) * TSEG + half8, wv);
    }
  }
#pragma unroll
  for (int k = 0; k < 8; ++k)
    fma8(acc, lxw + (120 + k) * TSEG + half8, ring[k]);
}

// ------------------------------------------------------- core math NT8 ----
// Lane = 2 cols (float2 weight) x 8 tokens. 16 FMA/row-visit.
__device__ __forceinline__ void fma8_2(float2* __restrict__ acc,
                                       const float* __restrict__ xr, float2 wv) {
  float xs[8];
  *(float4*)&xs[0] = *(const float4*)(xr);
  *(float4*)&xs[4] = *(const float4*)(xr + 4);
#pragma unroll
  for (int t = 0; t < 8; ++t) {
    acc[t].x = fmaf(xs[t], wv.x, acc[t].x);
    acc[t].y = fmaf(xs[t], wv.y, acc[t].y);
  }
}

__device__ __forceinline__ void accum128_8(float2* __restrict__ acc,
                                           const float2* __restrict__ wp2,
                                           const float* __restrict__ lxw) {
  float2 ring[8];
#pragma unroll
  for (int k = 0; k < 8; ++k) ring[k] = wp2[(size_t)k * 2048];
  for (int i0 = 0; i0 + 8 < 128; i0 += 8) {
#pragma unroll
    for (int k = 0; k < 8; ++k) {
      float2 wv = ring[k];
      ring[k] = wp2[(size_t)(i0 + 8 + k) * 2048];
      fma8_2(acc, lxw + (i0 + k) * TSEG, wv);
    }
  }
#pragma unroll
  for (int k = 0; k < 8; ++k)
    fma8_2(acc, lxw + (120 + k) * TSEG, ring[k]);
}

// ---------------------------------------------------------------- stage ----
__device__ __forceinline__ void stage512(float* __restrict__ lx,
                                         const float* __restrict__ src, int tid) {
  const float4* s4 = (const float4*)src;
  float4* d4 = (float4*)lx;
#pragma unroll
  for (int k = 0; k < 8; ++k) d4[k * 256 + tid] = s4[k * 256 + tid];
}

__device__ __forceinline__ void stage_silu512(float* __restrict__ lx,
                                              const float* __restrict__ h1p,
                                              const float* __restrict__ h3p, int tid) {
  const float4* a4 = (const float4*)h1p;
  const float4* b4 = (const float4*)h3p;
  float4* d4 = (float4*)lx;
#pragma unroll
  for (int k = 0; k < 8; ++k) {
    float4 a = a4[k * 256 + tid];
    float4 b = b4[k * 256 + tid];
    float4 g;
    g.x = (a.x / (1.f + __expf(-a.x))) * b.x;
    g.y = (a.y / (1.f + __expf(-a.y))) * b.y;
    g.z = (a.z / (1.f + __expf(-a.z))) * b.z;
    g.w = (a.w / (1.f + __expf(-a.w))) * b.w;
    d4[k * 256 + tid] = g;
  }
}

// ------------------------------------------------------- reduce (NT16) ----
__device__ __forceinline__ void red_write(float* __restrict__ lds,
                                          const float4* __restrict__ acc, int tid) {
  int l = tid & 63;
  int w = tid >> 6;
  float tmp[32];
#pragma unroll
  for (int t = 0; t < 8; ++t) {
    tmp[t] = acc[t].x;
    tmp[8 + t] = acc[t].y;
    tmp[16 + t] = acc[t].z;
    tmp[24 + t] = acc[t].w;
  }
  float* rp = lds + (size_t)(w * 64 + l) * RSTR;
#pragma unroll
  for (int q = 0; q < 32; q += 4) *(float4*)(rp + q) = *(const float4*)&tmp[q];
}

__device__ __forceinline__ void red_read(const float* __restrict__ lds,
                                         float* __restrict__ v, int tid) {
  int col = tid & 127;
  int half = tid >> 7;
  int base = (half * 32 + (col >> 2)) * RSTR + (col & 3) * 8;
#pragma unroll
  for (int t = 0; t < 8; ++t) {
    float sum = 0.f;
#pragma unroll
    for (int w = 0; w < 4; ++w) sum += lds[w * 64 * RSTR + base + t];
    v[t] = sum;
  }
}

// -------------------------------------------------------- reduce (NT8) ----
__device__ __forceinline__ void red_write8(float* __restrict__ lds,
                                           const float2* __restrict__ acc, int tid) {
  int l = tid & 63;
  int w = tid >> 6;
  float tmp[16];
#pragma unroll
  for (int t = 0; t < 8; ++t) {
    tmp[t] = acc[t].x;
    tmp[8 + t] = acc[t].y;
  }
  float* rp = lds + (size_t)(w * 64 + l) * RSTR8;
#pragma unroll
  for (int q = 0; q < 16; q += 4) *(float4*)(rp + q) = *(const float4*)&tmp[q];
}

__device__ __forceinline__ void red_read8(const float* __restrict__ lds,
                                          float* __restrict__ v, int col) {
  int base = (col >> 1) * RSTR8 + (col & 1) * 8;
#pragma unroll
  for (int t = 0; t < 8; ++t) {
    float sum = 0.f;
#pragma unroll
    for (int w = 0; w < 4; ++w) sum += lds[w * 64 * RSTR8 + base + t];
    v[t] = sum;
  }
}

// --------------------------------------------------------------- passB ----
// Block: one matrix, 128 f-cols, all 4096 h-rows; 8 chunks of 512 rows,
// 4 waves x 128 rows each. NT branch on c<=8 halves FMA + reduce work.
__global__ __launch_bounds__(256) void passB13_kernel(const float* __restrict__ W1,
                                                      const float* __restrict__ W3,
                                                      const float* __restrict__ xseg,
                                                      float* __restrict__ h1seg,
                                                      float* __restrict__ h3seg,
                                                      const int* __restrict__ cnt,
                                                      const int* __restrict__ ord) {
  __shared__ float lds[4 * 64 * RSTR];  // 36.9 KB (>= 32 KB stage)
  int gy = blockIdx.y;
  int s = ord[gy >> 1];
  int mat = gy & 1;
  int c = cnt[s];
  if (c == 0) return;
  int e = s >> 1;
  int tid = threadIdx.x;
  int l = tid & 63;
  int w = tid >> 6;
  int colbase = blockIdx.x * 128;
  const float* Wbase = (mat ? W3 : W1) + (size_t)e * HH * FF + colbase;
  const float* xsrc = xseg + (size_t)s * HH * TSEG;
  float* segbase = (mat ? h3seg : h1seg) + ((size_t)s * FF + colbase) * TSEG;
  if (c <= 8) {
    const float2* wp2 = (const float2*)Wbase + l;
    float2 acc[8];
#pragma unroll
    for (int t = 0; t < 8; ++t) acc[t] = make_float2(0.f, 0.f);
    for (int ch = 0; ch < HH / CH; ++ch) {
      __syncthreads();
      stage512(lds, xsrc + (size_t)(ch * CH) * TSEG, tid);
      __syncthreads();
      accum128_8(acc, wp2 + (size_t)(ch * CH + w * 128) * 2048,
                 lds + (w * 128) * TSEG);
    }
    __syncthreads();
    red_write8(lds, acc, tid);
    __syncthreads();
    if (tid < 128) {
      float v[8];
      red_read8(lds, v, tid);
      float* seg = segbase + (size_t)tid * TSEG;
      *(float4*)(seg) = *(const float4*)&v[0];
      *(float4*)(seg + 4) = *(const float4*)&v[4];
    }
  } else {
    const float* Wm = Wbase + (l & 31) * 4;
    int half8 = (l >> 5) * 8;
    float4 acc[8];
#pragma unroll
    for (int t = 0; t < 8; ++t) acc[t] = make_float4(0.f, 0.f, 0.f, 0.f);
    for (int ch = 0; ch < HH / CH; ++ch) {
      __syncthreads();
      stage512(lds, xsrc + (size_t)(ch * CH) * TSEG, tid);
      __syncthreads();
      const float4* wp4 = (const float4*)(Wm + (size_t)(ch * CH + w * 128) * FF);
      accum128(acc, wp4, lds + (w * 128) * TSEG, half8);
    }
    __syncthreads();
    red_write(lds, acc, tid);
    __syncthreads();
    float v[8];
    red_read(lds, v, tid);
    int col = tid & 127;
    int half = tid >> 7;
    float* seg = segbase + (size_t)col * TSEG + half * 8;
    *(float4*)(seg) = *(const float4*)&v[0];
    *(float4*)(seg + 4) = *(const float4*)&v[4];
  }
}

// --------------------------------------------------------------- passC ----
// Block: 128 h-cols, rows [z*2048,+2048) of W2 (4 chunks); silu fused in
// staging; NT branch mirrors passB (NT8 reads only tokens 0..7).
__global__ __launch_bounds__(256) void passC13_kernel(const float* __restrict__ W2,
                                                      const float* __restrict__ h1seg,
                                                      const float* __restrict__ h3seg,
                                                      const int* __restrict__ cnt,
                                                      const int* __restrict__ tok,
                                                      const float* __restrict__ wts,
                                                      const int* __restrict__ ord,
                                                      float* __restrict__ out) {
  __shared__ float lds[4 * 64 * RSTR];
  __shared__ int stok[TSEG];
  __shared__ float swt[TSEG];
  int gy = blockIdx.y;
  int s = ord[gy >> 1];
  int z = gy & 1;
  int c = cnt[s];
  if (c == 0) return;
  int e = s >> 1;
  int tid = threadIdx.x;
  int l = tid & 63;
  int w = tid >> 6;
  int colbase = blockIdx.x * 128;
  if (tid < TSEG) {
    stok[tid] = tok[s * TSEG + tid];
    swt[tid] = wts[s * TSEG + tid];
  }
  const float* Wbase = W2 + (size_t)e * FF * HH + (size_t)(z * 2048) * HH + colbase;
  const float* h1src = h1seg + ((size_t)s * FF + z * 2048) * TSEG;
  const float* h3src = h3seg + ((size_t)s * FF + z * 2048) * TSEG;
  if (c <= 8) {
    const float2* wp2 = (const float2*)Wbase + l;
    float2 acc[8];
#pragma unroll
    for (int t = 0; t < 8; ++t) acc[t] = make_float2(0.f, 0.f);
    for (int ch = 0; ch < 4; ++ch) {
      __syncthreads();
      stage_silu512(lds, h1src + (size_t)(ch * CH) * TSEG,
                    h3src + (size_t)(ch * CH) * TSEG, tid);
      __syncthreads();
      accum128_8(acc, wp2 + (size_t)(ch * CH + w * 128) * 2048,
                 lds + (w * 128) * TSEG);
    }
    __syncthreads();
    red_write8(lds, acc, tid);
    __syncthreads();
    if (tid < 128) {
      float v[8];
      red_read8(lds, v, tid);
      float* op = out + colbase + tid;
#pragma unroll
      for (int t = 0; t < 8; ++t) {
        if (t < c) atomicAdd(op + (size_t)stok[t] * HH, swt[t] * v[t]);
      }
    }
  } else {
    const float* Wm = Wbase + (l & 31) * 4;
    int half8 = (l >> 5) * 8;
    float4 acc[8];
#pragma unroll
    for (int t = 0; t < 8; ++t) acc[t] = make_float4(0.f, 0.f, 0.f, 0.f);
    for (int ch = 0; ch < 4; ++ch) {
      __syncthreads();
      stage_silu512(lds, h1src + (size_t)(ch * CH) * TSEG,
                    h3src + (size_t)(ch * CH) * TSEG, tid);
      __syncthreads();
      const float4* wp4 = (const float4*)(Wm + (size_t)(ch * CH + w * 128) * HH);
      accum128(acc, wp4, lds + (w * 128) * TSEG, half8);
    }
    __syncthreads();
    red_write(lds, acc, tid);
    __syncthreads();
    float v[8];
    red_read(lds, v, tid);
    int col = tid & 127;
    int half = tid >> 7;
    float* op = out + colbase + col;
#pragma unroll
    for (int t = 0; t < 8; ++t) {
      int tt = half * 8 + t;
      if (tt < c) atomicAdd(op + (size_t)stok[tt] * HH, swt[tt] * v[t]);
    }
  }
}

// -------------------------------------------------------------- launch ----
extern "C" void kernel_launch(void* const* d_in, const int* in_sizes, int n_in,
                              void* d_out, int out_size, void* d_ws, size_t ws_size,
                              hipStream_t stream) {
  const float* x  = (const float*)d_in[0];
  const float* Wg = (const float*)d_in[1];
  const float* W1 = (const float*)d_in[2];
  const float* W3 = (const float*)d_in[3];
  const float* W2 = (const float*)d_in[4];
  float* out = (float*)d_out;

  char* ws = (char*)d_ws;
  float* logits = (float*)ws;                 // 256 f32
  int*   cnt    = (int*)(ws + 1024);          // 16 i32
  int*   tok    = (int*)(ws + 1088);          // 256 i32
  float* wts    = (float*)(ws + 2112);        // 256 f32
  int*   ord    = (int*)(ws + 3136);          // 16 i32
  float* xseg   = (float*)(ws + 4096);                 // 4 MB
  float* h1seg  = xseg + (size_t)NSLOT * HH * TSEG;    // 4 MB
  float* h3seg  = h1seg + (size_t)NSLOT * FF * TSEG;   // 4 MB

  hipMemsetAsync(d_out, 0, (size_t)out_size * sizeof(float), stream);
  gate_kernel<<<BB, 256, 0, stream>>>(x, Wg, logits);
  route_kernel<<<1, 64, 0, stream>>>(logits, cnt, tok, wts, ord);
  buildx_kernel<<<dim3(HH / 256, NSLOT), 256, 0, stream>>>(x, cnt, tok, xseg);
  passB13_kernel<<<dim3(FF / 128, NSLOT * 2), 256, 0, stream>>>(W1, W3, xseg, h1seg, h3seg, cnt, ord);
  passC13_kernel<<<dim3(HH / 128, NSLOT * 2), 256, 0, stream>>>(W2, h1seg, h3seg, cnt, tok, wts, ord, out);
}